// Round 1
// baseline (297.804 us; speedup 1.0000x reference)
//
#include <hip/hip_runtime.h>

#define DI __device__ __forceinline__

typedef unsigned short u16;
typedef unsigned int u32;
typedef float f32x4 __attribute__((ext_vector_type(4)));
typedef short bf16x8 __attribute__((ext_vector_type(8)));
typedef u16 u16x8 __attribute__((ext_vector_type(8)));
typedef u16 u16x4 __attribute__((ext_vector_type(4)));

// Problem constants
constexpr int SQ = 2048;      // sequence
constexpr int HDIM = 1024;    // hidden
constexpr int NHEAD = 16;
constexpr int DH = 64;        // head dim
constexpr int MT = 4096;      // B*S rows

// ws byte offsets
constexpr size_t OFF_XB = 0;                  // x bf16 [4096][1024]  8388608 B
constexpr size_t OFF_WB = 8388608;            // Wq,Wk,Wv,Wo bf16 4x[1024][1024] 8388608 B
constexpr size_t OFF_QH = 16777216;           // q heads bf16 [B][NH][S][64] 8388608 B
constexpr size_t OFF_KH = 25165824;           // k heads
constexpr size_t OFF_VH = 33554432;           // v heads (pre-transpose)
constexpr size_t OFF_VT = 41943040;           // v transposed [B][NH][64][S]
constexpr size_t OFF_AT = 50331648;           // attn out bf16 [4096][1024]
constexpr size_t OFF_Y  = 58720256;           // y f32 [4096][1024] 16777216 B
// total 75497472 bytes

DI u16 f2bf(float f) {
  u32 u = __float_as_uint(f);
  u += 0x7FFFu + ((u >> 16) & 1u);   // RNE
  return (u16)(u >> 16);
}
DI float bf2f(u16 h) { return __uint_as_float(((u32)h) << 16); }

typedef __attribute__((address_space(1))) const void gas_t;
typedef __attribute__((address_space(3))) void las_t;
DI void gload_lds16(const void* g, void* l) {
  __builtin_amdgcn_global_load_lds((gas_t*)g, (las_t*)l, 16, 0, 0);
}

// ---------------- fp32 -> bf16 converts ----------------
__global__ __launch_bounds__(256) void cvt_x(const float* __restrict__ src, u16* __restrict__ dst) {
  int i = blockIdx.x * 256 + threadIdx.x;      // 524288 groups of 8
  const float4* s = (const float4*)src + (size_t)i * 2;
  float4 a = s[0], b = s[1];
  u16x8 o;
  o[0]=f2bf(a.x); o[1]=f2bf(a.y); o[2]=f2bf(a.z); o[3]=f2bf(a.w);
  o[4]=f2bf(b.x); o[5]=f2bf(b.y); o[6]=f2bf(b.z); o[7]=f2bf(b.w);
  *((u16x8*)dst + i) = o;
}

__global__ __launch_bounds__(256) void cvt_w4(const float* __restrict__ w0, const float* __restrict__ w1,
                                              const float* __restrict__ w2, const float* __restrict__ w3,
                                              u16* __restrict__ dst) {
  int z = blockIdx.z;
  const float* src = (z==0)?w0:(z==1)?w1:(z==2)?w2:w3;
  int i = blockIdx.x * 256 + threadIdx.x;      // 131072 groups of 8 per weight
  const float4* s = (const float4*)src + (size_t)i * 2;
  float4 a = s[0], b = s[1];
  u16x8 o;
  o[0]=f2bf(a.x); o[1]=f2bf(a.y); o[2]=f2bf(a.z); o[3]=f2bf(a.w);
  o[4]=f2bf(b.x); o[5]=f2bf(b.y); o[6]=f2bf(b.z); o[7]=f2bf(b.w);
  *((u16x8*)(dst + (size_t)z * 1048576) + i) = o;
}

// ---------------- 128x128 bf16 MFMA GEMM: C = A * W^T (+bias, epilogues) ----------------
// A: [4096][1024] bf16 row-major, W: [1024][1024] bf16 row-major (N-major, K contig)
// MODE 0: out bf16 scattered to head layout [B][NH][S][64] (+bias)
// MODE 1: out f32 y = acc + bias + resid (fp32 residual)
template<int MODE>
__global__ __launch_bounds__(256) void gemm128(const u16* __restrict__ A, const u16* __restrict__ Wall,
    const float* __restrict__ b0, const float* __restrict__ b1, const float* __restrict__ b2,
    const float* __restrict__ resid, u16* __restrict__ outH, float* __restrict__ outY)
{
  __shared__ u16 lds[2][4096];   // A-tile [128][32], W-tile [128][32]
  const int z = blockIdx.z;
  const u16* W = Wall + (size_t)z * 1048576;
  const float* bias = (z==0) ? b0 : (z==1) ? b1 : b2;
  const int bx = blockIdx.x, by = blockIdx.y;
  const int tid = threadIdx.x, wave = tid >> 6, lane = tid & 63;
  const int lo = lane & 15, hi = lane >> 4;
  const int wm = wave >> 1, wn = wave & 1;
  f32x4 acc[4][4] = {};
  const u16* Ab = A + (size_t)(by * 128) * 1024;
  const u16* Wb = W + (size_t)(bx * 128) * 1024;
  const int r0 = wave * 32, r1 = wave * 32 + 16;
  const int lrow = lane >> 2, lcol = (lane & 3) * 8;   // u16 units

  for (int kt = 0; kt < 32; ++kt) {
    const int kc = kt * 32;
    gload_lds16(Ab + (size_t)(r0 + lrow) * 1024 + kc + lcol, &lds[0][r0 * 32]);
    gload_lds16(Ab + (size_t)(r1 + lrow) * 1024 + kc + lcol, &lds[0][r1 * 32]);
    gload_lds16(Wb + (size_t)(r0 + lrow) * 1024 + kc + lcol, &lds[1][r0 * 32]);
    gload_lds16(Wb + (size_t)(r1 + lrow) * 1024 + kc + lcol, &lds[1][r1 * 32]);
    __syncthreads();
    bf16x8 af[4], bf[4];
    #pragma unroll
    for (int mi = 0; mi < 4; ++mi) af[mi] = *(const bf16x8*)&lds[0][(wm*64 + mi*16 + lo)*32 + hi*8];
    #pragma unroll
    for (int ni = 0; ni < 4; ++ni) bf[ni] = *(const bf16x8*)&lds[1][(wn*64 + ni*16 + lo)*32 + hi*8];
    #pragma unroll
    for (int mi = 0; mi < 4; ++mi)
      #pragma unroll
      for (int ni = 0; ni < 4; ++ni)
        acc[mi][ni] = __builtin_amdgcn_mfma_f32_16x16x32_bf16(af[mi], bf[ni], acc[mi][ni], 0, 0, 0);
    __syncthreads();
  }

  #pragma unroll
  for (int mi = 0; mi < 4; ++mi) {
    #pragma unroll
    for (int ni = 0; ni < 4; ++ni) {
      const int gn = bx*128 + wn*64 + ni*16 + lo;
      const float bv = bias[gn];
      #pragma unroll
      for (int r = 0; r < 4; ++r) {
        const int gm = by*128 + wm*64 + mi*16 + hi*4 + r;
        float v = acc[mi][ni][r] + bv;
        if (MODE == 0) {
          const int b = gm >> 11, s = gm & 2047, hh = gn >> 6, d = gn & 63;
          outH[(size_t)z * 4194304 + ((((size_t)b*16 + hh)*2048 + s)*64 + d)] = f2bf(v);
        } else {
          const size_t idx = (size_t)gm * 1024 + gn;
          outY[idx] = v + resid[idx];
        }
      }
    }
  }
}

// ---------------- V transpose: [B][NH][S][64] -> [B][NH][64][S] ----------------
__global__ __launch_bounds__(256) void transpose_v(const u16* __restrict__ vh, u16* __restrict__ vT) {
  __shared__ u16 t[64][72];
  const int bh = blockIdx.y, st = blockIdx.x * 64;
  const u16* src = vh + ((size_t)bh * 2048 + st) * 64;
  u16* dst = vT + (size_t)bh * 131072 + st;
  const int tid = threadIdx.x;
  #pragma unroll
  for (int i = 0; i < 4; ++i) {
    int idx = tid + i * 256;
    int r = idx >> 4, c = (idx & 15) * 4;
    *(u16x4*)&t[r][c] = *(const u16x4*)&src[r * 64 + c];
  }
  __syncthreads();
  #pragma unroll
  for (int i = 0; i < 4; ++i) {
    int idx = tid + i * 256;
    int d = idx >> 4, s4 = (idx & 15) * 4;
    u16x4 o;
    o[0] = t[s4+0][d]; o[1] = t[s4+1][d]; o[2] = t[s4+2][d]; o[3] = t[s4+3][d];
    *(u16x4*)&dst[(size_t)d * 2048 + s4] = o;
  }
}

// ---------------- fused attention ----------------
// grid (64, 32): x = q-tile (32 rows), y = b*16+h. 512 threads (8 waves), wave w owns k-strip [w*256, w*256+256)
// LDS: es[2048 rows][64B] (32 q cols bf16, XOR-swizzled) = 131072 B, then small reduce arrays.
// math: s = qk/8 + mask[k]; es = exp(s); L = sum_k es; p = es/L; ep = exp(p); S2 = sum ep; D = S2+1e-6
//       cw = p2*sigmoid(p2), p2 = ep/D; sigmoid(x) ~= 0.5 + x/4 (|x|<=1.4e-3, err ~5e-11)
//       => attn = (0.5/D)*sum(ep*v) + (0.25/D^2)*sum(ep^2*v)
__global__ __launch_bounds__(512, 1) void attn_fused(
    const u16* __restrict__ qh, const u16* __restrict__ kh, const u16* __restrict__ vT,
    const float* __restrict__ mask, u16* __restrict__ attnb)
{
  extern __shared__ char smem[];
  float* red = (float*)(smem + 131072);  // [0..255] Lpart, [256..511] S2part, [512..543] rL, [544..575] c1, [576..607] c2
  const int bh = blockIdx.y, qt = blockIdx.x;
  const int tid = threadIdx.x, w = tid >> 6, lane = tid & 63;
  const int lo = lane & 15, hi = lane >> 4;
  const u16* Q  = qh + ((size_t)bh * 2048 + qt * 32) * 64;
  const u16* Kp = kh + (size_t)bh * 131072;
  const u16* Vp = vT + (size_t)bh * 131072;
  const float* mrow = mask + (size_t)(bh >> 4) * 2048;

  bf16x8 qa[2][2];
  #pragma unroll
  for (int mi = 0; mi < 2; ++mi)
    #pragma unroll
    for (int dh = 0; dh < 2; ++dh)
      qa[mi][dh] = *(const bf16x8*)&Q[(mi*16 + lo)*64 + dh*32 + hi*8];

  // ---- pass 1: QK^T -> exp(s) -> es LDS (bf16, [k][q] layout), accumulate L ----
  float Lacc[2][4] = {{0,0,0,0},{0,0,0,0}};
  #pragma unroll 2
  for (int kt = 0; kt < 16; ++kt) {
    const int k0 = w * 256 + kt * 16;
    const u16* Krow = &Kp[(size_t)(k0 + lo) * 64 + hi * 8];
    bf16x8 kb0 = *(const bf16x8*)&Krow[0];
    bf16x8 kb1 = *(const bf16x8*)&Krow[32];
    const float mk = mrow[k0 + lo];
    const int k = k0 + lo;
    const int swz = ((k + (k >> 3)) & 3) << 4;
    #pragma unroll
    for (int mi = 0; mi < 2; ++mi) {
      f32x4 a = {0.f, 0.f, 0.f, 0.f};
      a = __builtin_amdgcn_mfma_f32_16x16x32_bf16(qa[mi][0], kb0, a, 0, 0, 0);
      a = __builtin_amdgcn_mfma_f32_16x16x32_bf16(qa[mi][1], kb1, a, 0, 0, 0);
      float e0 = __expf(a[0]*0.125f + mk);
      float e1 = __expf(a[1]*0.125f + mk);
      float e2 = __expf(a[2]*0.125f + mk);
      float e3 = __expf(a[3]*0.125f + mk);
      Lacc[mi][0] += e0; Lacc[mi][1] += e1; Lacc[mi][2] += e2; Lacc[mi][3] += e3;
      uint2 pk;
      pk.x = (u32)f2bf(e0) | ((u32)f2bf(e1) << 16);
      pk.y = (u32)f2bf(e2) | ((u32)f2bf(e3) << 16);
      *(uint2*)(smem + (size_t)k * 64 + ((mi*32 + hi*8) ^ swz)) = pk;  // rows q=mi*16+hi*4..+4, col k
    }
  }
  #pragma unroll
  for (int mi = 0; mi < 2; ++mi)
    #pragma unroll
    for (int r = 0; r < 4; ++r) {
      float v = Lacc[mi][r];
      v += __shfl_xor(v, 1); v += __shfl_xor(v, 2);
      v += __shfl_xor(v, 4); v += __shfl_xor(v, 8);
      Lacc[mi][r] = v;
    }
  if (lo == 0) {
    #pragma unroll
    for (int mi = 0; mi < 2; ++mi)
      #pragma unroll
      for (int r = 0; r < 4; ++r)
        red[w*32 + mi*16 + hi*4 + r] = Lacc[mi][r];
  }
  __syncthreads();
  if (tid < 32) {
    float L = 0.f;
    #pragma unroll
    for (int ww = 0; ww < 8; ++ww) L += red[ww*32 + tid];
    red[512 + tid] = 1.0f / L;
  }
  __syncthreads();

  // ---- pass 1.5: ep = exp(es * rL), overwrite es in place, accumulate S2 ----
  float rl[8];
  {
    const int qo = lane & 3;
    #pragma unroll
    for (int j = 0; j < 8; ++j) rl[j] = red[512 + qo*8 + j];
  }
  float S2acc[8] = {0,0,0,0,0,0,0,0};
  #pragma unroll 2
  for (int it = 0; it < 16; ++it) {
    const int r = w * 256 + it * 16 + (lane >> 2);
    const int swz = ((r + (r >> 3)) & 3) << 4;
    char* p = smem + (size_t)r * 64 + (((lane & 3) * 16) ^ swz);
    u16x8 ev = *(u16x8*)p;
    u16x8 eo;
    #pragma unroll
    for (int j = 0; j < 8; ++j) {
      float ep = __expf(bf2f(ev[j]) * rl[j]);
      S2acc[j] += ep;
      eo[j] = f2bf(ep);
    }
    *(u16x8*)p = eo;
  }
  #pragma unroll
  for (int j = 0; j < 8; ++j) {
    float v = S2acc[j];
    v += __shfl_xor(v, 4);  v += __shfl_xor(v, 8);
    v += __shfl_xor(v, 16); v += __shfl_xor(v, 32);
    S2acc[j] = v;
  }
  if ((lane >> 2) == 0) {
    #pragma unroll
    for (int j = 0; j < 8; ++j) red[256 + w*32 + (lane & 3)*8 + j] = S2acc[j];
  }
  __syncthreads();
  if (tid < 32) {
    float S2 = 0.f;
    #pragma unroll
    for (int ww = 0; ww < 8; ++ww) S2 += red[256 + ww*32 + tid];
    const float rD = 1.0f / (S2 + 1e-6f);
    red[544 + tid] = 0.5f  * rD;
    red[576 + tid] = 0.25f * rD * rD;
  }
  __syncthreads();

  // ---- pass 2: O1 = sum ep*v, O2 = sum ep^2*v over this wave's k-strip ----
  f32x4 o1[2][4] = {}, o2[2][4] = {};
  #pragma unroll 1
  for (int ks = 0; ks < 8; ++ks) {
    const int kb = w * 256 + ks * 32;
    bf16x8 vb[4];
    #pragma unroll
    for (int ni = 0; ni < 4; ++ni)
      vb[ni] = *(const bf16x8*)&Vp[(size_t)(ni*16 + lo) * 2048 + kb + hi*8];
    #pragma unroll
    for (int mi = 0; mi < 2; ++mi) {
      bf16x8 a1, a2;
      #pragma unroll
      for (int j = 0; j < 8; ++j) {
        const int k = kb + hi*8 + j;
        const int swz = ((k + (k >> 3)) & 3) << 4;
        const u16 wv = *(const u16*)(smem + (size_t)k * 64 + ((mi*32 + lo*2) ^ swz));
        a1[j] = (short)wv;
        const float e = bf2f(wv);
        a2[j] = (short)f2bf(e * e);
      }
      #pragma unroll
      for (int ni = 0; ni < 4; ++ni) {
        o1[mi][ni] = __builtin_amdgcn_mfma_f32_16x16x32_bf16(a1, vb[ni], o1[mi][ni], 0, 0, 0);
        o2[mi][ni] = __builtin_amdgcn_mfma_f32_16x16x32_bf16(a2, vb[ni], o2[mi][ni], 0, 0, 0);
      }
    }
  }

  // ---- cross-wave reduce (reuse es region; wave w's region == its own strip) ----
  __syncthreads();
  float* ow = (float*)smem + (size_t)w * 4096;   // [2][32][64] f32 = 16KB per wave
  #pragma unroll
  for (int mi = 0; mi < 2; ++mi)
    #pragma unroll
    for (int ni = 0; ni < 4; ++ni)
      #pragma unroll
      for (int r = 0; r < 4; ++r) {
        const int q = mi*16 + hi*4 + r, d = ni*16 + lo;
        ow[q*64 + d]        = o1[mi][ni][r];
        ow[2048 + q*64 + d] = o2[mi][ni][r];
      }
  __syncthreads();
  const float* sf = (const float*)smem;
  u16* arow = attnb + ((size_t)(bh >> 4) * 2048 + qt * 32) * 1024 + (bh & 15) * 64;
  #pragma unroll
  for (int i = 0; i < 4; ++i) {
    const int idx = tid + i * 512;     // 0..2047
    const int q = idx >> 6, d = idx & 63;
    float v1 = 0.f, v2 = 0.f;
    #pragma unroll
    for (int ww = 0; ww < 8; ++ww) {
      v1 += sf[ww*4096 + q*64 + d];
      v2 += sf[ww*4096 + 2048 + q*64 + d];
    }
    const float att = red[544 + q] * v1 + red[576 + q] * v2;
    arow[(size_t)q * 1024 + d] = f2bf(att);
  }
}

// ---------------- LayerNorm with Quake-III inv-sqrt replication ----------------
__global__ __launch_bounds__(256) void layernorm_k(const float* __restrict__ y, const float* __restrict__ nw,
                                                   const float* __restrict__ nb, float* __restrict__ out)
{
  const int row = blockIdx.x;
  const float* yr = y + (size_t)row * 1024;
  const int tid = threadIdx.x;
  float4 x = *(const float4*)&yr[tid * 4];
  float s  = x.x + x.y + x.z + x.w;
  float s2 = x.x*x.x + x.y*x.y + x.z*x.z + x.w*x.w;
  #pragma unroll
  for (int m = 1; m < 64; m <<= 1) { s += __shfl_xor(s, m); s2 += __shfl_xor(s2, m); }
  __shared__ float rs[4], rs2[4];
  const int wv = tid >> 6;
  if ((tid & 63) == 0) { rs[wv] = s; rs2[wv] = s2; }
  __syncthreads();
  s  = rs[0] + rs[1] + rs[2] + rs[3];
  s2 = rs2[0] + rs2[1] + rs2[2] + rs2[3];
  const float mean = s * (1.0f / 1024.0f);
  const float var  = s2 * (1.0f / 1024.0f) - mean * mean;
  const float r = var + 1e-5f;
  int ib = __float_as_int(r);
  ib = 1597463007 - (ib >> 1);
  const float y0 = __int_as_float(ib);
  const float inv = y0 * (1.5f - 0.5f * r * y0 * y0);
  float4 w4 = *(const float4*)&nw[tid * 4];
  float4 b4 = *(const float4*)&nb[tid * 4];
  float4 o;
  o.x = w4.x * ((x.x - mean) * inv) + b4.x;
  o.y = w4.y * ((x.y - mean) * inv) + b4.y;
  o.z = w4.z * ((x.z - mean) * inv) + b4.z;
  o.w = w4.w * ((x.w - mean) * inv) + b4.w;
  *(float4*)&out[(size_t)row * 1024 + tid * 4] = o;
}

extern "C" void kernel_launch(void* const* d_in, const int* in_sizes, int n_in,
                              void* d_out, int out_size, void* d_ws, size_t ws_size,
                              hipStream_t stream)
{
  const float* x    = (const float*)d_in[0];
  const float* mask = (const float*)d_in[1];
  const float* Wq   = (const float*)d_in[2];
  const float* bq   = (const float*)d_in[3];
  const float* Wk   = (const float*)d_in[4];
  const float* bk   = (const float*)d_in[5];
  const float* Wv   = (const float*)d_in[6];
  const float* bv   = (const float*)d_in[7];
  const float* Wo   = (const float*)d_in[8];
  const float* bo   = (const float*)d_in[9];
  const float* nw   = (const float*)d_in[10];
  const float* nb   = (const float*)d_in[11];
  float* out = (float*)d_out;
  char* ws = (char*)d_ws;
  u16* xb    = (u16*)(ws + OFF_XB);
  u16* wb    = (u16*)(ws + OFF_WB);
  u16* qhp   = (u16*)(ws + OFF_QH);
  u16* vhp   = (u16*)(ws + OFF_VH);
  u16* kh    = (u16*)(ws + OFF_KH);
  u16* vT    = (u16*)(ws + OFF_VT);
  u16* attnb = (u16*)(ws + OFF_AT);
  float* y   = (float*)(ws + OFF_Y);
  (void)in_sizes; (void)n_in; (void)out_size; (void)ws_size; (void)kh;

  hipFuncSetAttribute((const void*)attn_fused, hipFuncAttributeMaxDynamicSharedMemorySize, 133504);

  cvt_x<<<2048, 256, 0, stream>>>(x, xb);
  cvt_w4<<<dim3(512, 1, 4), 256, 0, stream>>>(Wq, Wk, Wv, Wo, wb);
  gemm128<0><<<dim3(8, 32, 3), 256, 0, stream>>>(xb, wb, bq, bk, bv, nullptr, qhp, nullptr);
  transpose_v<<<dim3(32, 32), 256, 0, stream>>>(vhp, vT);
  attn_fused<<<dim3(64, 32), 512, 133504, stream>>>(qhp, (u16*)(ws + OFF_KH), vT, mask, attnb);
  gemm128<1><<<dim3(8, 32, 1), 256, 0, stream>>>(attnb, wb + 3*1048576, bo, nullptr, nullptr, x, nullptr, y);
  layernorm_k<<<4096, 256, 0, stream>>>(y, nw, nb, out);
}